// Round 5
// baseline (45981.320 us; speedup 1.0000x reference)
//
// Round 9: split-K L1. L0 = round-4 verbatim (proven 28.0ms engine).
// L1 = 64 n-tiles x 24 h-cols x 2 K-halves = 128 blocks (grid still 224):
//   ktile0 reads ONLY h0 (12 windows), ktile1 reads ONLY h1 (12 windows)
//   -> per-block staging halves (768KB -> 384KB/step); ktile1 never waits c0.
//   Pair exchanges f32 partial gates (24KB) via workspace + pairwise flag;
//   each half does the cell update for its 64 batch rows. c1 group-bar makes
//   partial buffers single-buffer safe (writer can't lap reader).
// Same round-4 window engine (dmaoff/addrA/WAITVM8/LDSBAR) throughout.
#include <hip/hip_runtime.h>

#define TSTEPS 1024
#define BATCH  128
#define HDIM   1536
#define NB_L0  96
#define NB_L1  128
#define NBLK   (NB_L0 + NB_L1)
#define K0P    1600    // L0 packed K: [0,64)=x+pad, [64,1600)=W_hh0
#define K1H    1536    // L1 packed K per half

typedef _Float16 f16x8 __attribute__((ext_vector_type(8)));
typedef float    f32x4 __attribute__((ext_vector_type(4)));
typedef float    f32x2 __attribute__((ext_vector_type(2)));

// ---- workspace layout (bytes) ----
#define OFF_C0   0ul                                    // 8 lines x 128B
#define OFF_C1   1024ul                                 // 8 lines x 128B
#define OFF_H0   4096ul                                 // ring of 4 slots
#define OFF_H1   (OFF_H0 + 4ul*BATCH*HDIM*2)            // 2 slots
#define OFF_WP0  (OFF_H1 + 2ul*BATCH*HDIM*2)
#define OFF_WP1  (OFF_WP0 + 96ul*64*K0P*2)
#define OFF_WLP  (OFF_WP1 + 128ul*96*K1H*2)             // same bytes as before
#define OFF_PART (OFF_WLP + 16ul*HDIM*2)                // 128 x 64 x 96 f32
#define OFF_PFLG (OFF_PART + 128ul*64*96*4)             // 128 lines x 128B
#define WS_NEED  (OFF_PFLG + 128ul*128)                 // ~63.0 MB

// ---- dynamic LDS layout (bytes) — round-4 map (+bg widened) ----
#define SM_PARK  98304     // L1 park: 2 windows = 8 cl x 6KB = 48KB
#define SM_CST   147456    // L0: 8KB; L1: 6KB
#define SM_BG    155648    // L0: 64 f32; L1: 96 f32
#define SM_BYTES 156160

#define MFMA(a,b,c) __builtin_amdgcn_mfma_f32_16x16x32_f16(a,b,c,0,0,0)
#define LDSBAR()  asm volatile("s_waitcnt lgkmcnt(0)\n\ts_barrier" ::: "memory")
#define WAITVM8() asm volatile("s_waitcnt vmcnt(8)" ::: "memory")
#define WAITVM0() asm volatile("s_waitcnt vmcnt(0)" ::: "memory")

__device__ __forceinline__ float sgf(float x) { return 1.f/(1.f + __expf(-x)); }
__device__ __forceinline__ float thf(float x) { float e = __expf(2.f*x); return 1.f - 2.f/(e+1.f); }

__device__ __forceinline__ void gld16(const _Float16* g, char* lds) {
  __builtin_amdgcn_global_load_lds(
      (const __attribute__((address_space(1))) unsigned int*)g,
      (__attribute__((address_space(3))) unsigned int*)lds, 16, 0, 0);
}

// Group barrier: add 1 to my line (release), spin until all 8 lines hit
// per-line target, acquire, resync.
__device__ __forceinline__ void group_bar(unsigned* lines, unsigned target, int tid) {
  __syncthreads();   // all stores (incl. h) issued; drains vmcnt/lgkm
  if (tid == 0)
    __hip_atomic_fetch_add(lines + (blockIdx.x & 7)*32, 1u,
                           __ATOMIC_RELEASE, __HIP_MEMORY_SCOPE_AGENT);
  if (tid < 8) {
    while (__hip_atomic_load(lines + tid*32, __ATOMIC_RELAXED,
                             __HIP_MEMORY_SCOPE_AGENT) < target)
      __builtin_amdgcn_s_sleep(1);
    __builtin_amdgcn_fence(__ATOMIC_ACQUIRE, "agent");
  }
  __syncthreads();
}

// Cross-group wait (no add): poll other group's 8 lines to target, acquire.
__device__ __forceinline__ void wait_group(unsigned* lines, unsigned target, int tid) {
  if (tid < 8) {
    while (__hip_atomic_load(lines + tid*32, __ATOMIC_RELAXED,
                             __HIP_MEMORY_SCOPE_AGENT) < target)
      __builtin_amdgcn_s_sleep(1);
    __builtin_amdgcn_fence(__ATOMIC_ACQUIRE, "agent");
  }
  __syncthreads();
}

// ---- weight repack fp32 -> fp16 into per-block packed rows ----
__global__ void convert_weights(const float* __restrict__ Wih0, const float* __restrict__ Whh0,
                                const float* __restrict__ Wih1, const float* __restrict__ Whh1,
                                const float* __restrict__ Wlin,
                                _Float16* __restrict__ Wp0, _Float16* __restrict__ Wp1,
                                _Float16* __restrict__ Wlp) {
  const unsigned N0 = 96u*64u*K0P, N1 = 128u*96u*K1H, N2 = 16u*HDIM;
  const unsigned NT = N0 + N1 + N2;
  for (unsigned i = blockIdx.x*blockDim.x + threadIdx.x; i < NT; i += gridDim.x*blockDim.x) {
    if (i < N0) {           // L0: [blk 96][p 64][k 1600], p = gate*16 + j
      unsigned blk = i / (64u*K0P), r = i - blk*64u*K0P;
      unsigned p = r / K0P, kk = r - p*K0P;
      unsigned srow = (p>>4)*HDIM + blk*16 + (p&15);
      float v;
      if (kk < 64u) v = (kk < 6u) ? Wih0[srow*6 + kk] : 0.f;
      else          v = Whh0[(size_t)srow*HDIM + (kk-64u)];
      Wp0[i] = (_Float16)v;
    } else if (i < N0 + N1) { // L1: [blk 128][p 96][k 1536]; blk=ntile*2+kt
      unsigned ii = i - N0;
      unsigned blk = ii / (96u*K1H), r = ii - blk*96u*K1H;
      unsigned p = r / K1H, kk = r - p*K1H;
      unsigned ntile = blk >> 1, kt = blk & 1;
      unsigned srow = (p/24u)*HDIM + ntile*24u + (p%24u);
      float v = kt ? Whh1[(size_t)srow*HDIM + kk] : Wih1[(size_t)srow*HDIM + kk];
      Wp1[ii] = (_Float16)v;
    } else {                 // final linear 16 x 1536 (rows >=5 zero)
      unsigned ii = i - N0 - N1;
      unsigned rr = ii / HDIM, k = ii - rr*HDIM;
      Wlp[ii] = (_Float16)(rr < 5 ? Wlin[rr*HDIM + k] : 0.f);
    }
  }
}

__global__ __launch_bounds__(256, 1) void lstm_persistent(
    const float* __restrict__ xall,
    const float* __restrict__ bih0, const float* __restrict__ bhh0,
    const float* __restrict__ bih1, const float* __restrict__ bhh1,
    const float* __restrict__ blin,
    const _Float16* __restrict__ Wp0, const _Float16* __restrict__ Wp1,
    const _Float16* __restrict__ Wlp,
    _Float16* __restrict__ h0b, _Float16* __restrict__ h1b,
    unsigned* __restrict__ c0l, unsigned* __restrict__ c1l,
    float* __restrict__ out, float* __restrict__ part, unsigned* __restrict__ pflg)
{
  extern __shared__ __align__(16) char smem[];
  char*  park = smem + SM_PARK;
  float* cst  = (float*)(smem + SM_CST);
  float* bg   = (float*)(smem + SM_BG);
  float* gbuf = (float*)smem;            // epilogue overlay on staging

  const int tid = threadIdx.x, bid = blockIdx.x;
  const int wv = tid >> 6, lane = tid & 63, q = lane >> 4, l15 = lane & 15;
  const int BH = BATCH*HDIM;

  // DMA lane offsets: instr i stages rows [wv*32+i*4, +4), swizzled cols.
  int dmaoff[8];
#pragma unroll
  for (int i = 0; i < 8; ++i) {
    int m = wv*32 + i*4 + (lane>>4), w16 = lane & 15;
    int u = (w16 & 8) | ((w16 ^ (m & 7)) & 7);
    dmaoff[i] = m*HDIM + u*8;
  }
  // A-frag LDS byte addrs within a window buffer (this wave reads chunk #wv).
  const int uA = wv*4 + q;
  int addrA[8];
#pragma unroll
  for (int mt = 0; mt < 8; ++mt) {
    int m = mt*16 + l15;
    int swz = (uA & 8) | ((uA ^ (m & 7)) & 7);
    addrA[mt] = m*256 + swz*16;
  }

  if (bid < NB_L0) {
    // ================= LAYER 0 (round-4 verbatim): 13 windows ===============
    for (int p = tid; p < 64; p += 256) {
      int srow = (p>>4)*HDIM + (bid<<4) + (p&15);
      bg[p] = bih0[srow] + bhh0[srow];
    }
    for (int i = tid; i < BATCH*16; i += 256) cst[i] = 0.f;
    f16x8 bw[13][4];
#pragma unroll
    for (int wi = 0; wi < 13; ++wi)
#pragma unroll
      for (int nt = 0; nt < 4; ++nt)
        bw[wi][nt] = *(const f16x8*)(Wp0 + ((size_t)(bid*64 + nt*16 + l15))*K0P
                                         + (4*wi + wv)*32 + q*8);
    __syncthreads();

#pragma unroll 1
    for (int s = 0; s < TSTEPS; ++s) {
      // ring-overwrite guard: slot s&3 was read by L1 step s-3; wait it done.
      if (s >= 4) wait_group(c1l, 16u*(unsigned)(s-3), tid);

      const _Float16* h0r = h0b + (size_t)((s+3)&3)*BH;   // h0(s-1)
      _Float16*       h0w = h0b + (size_t)(s&3)*BH;       // h0(s)
      const float*    xs  = xall + (size_t)s*BATCH*6;

      // ---- prologue: DMA window1; plain-stage window0 (x-part + h cols 0..63)
#pragma unroll
      for (int i = 0; i < 8; ++i)
        gld16(h0r + 64 + dmaoff[i], smem + 32768 + (wv*8+i)*1024);
#pragma unroll
      for (int i = 0; i < 4; ++i) {          // x-part, slots u<8 of window0
        int sidx = i*256 + tid, m = sidx>>3, w8 = sidx&7;
        int u = w8 ^ (m & 7);
        f16x8 v = {0,0,0,0,0,0,0,0};
        if (u == 0) {
#pragma unroll
          for (int j = 0; j < 6; ++j) v[j] = (_Float16)xs[m*6 + j];
        }
        *(f16x8*)(smem + m*256 + w8*16) = v;
      }
#pragma unroll
      for (int i = 0; i < 4; ++i) {          // h cols [0,64) -> slots w in [8,16)
        int sidx = i*256 + tid, m = sidx>>3, w8 = sidx&7;
        int u8 = (w8 ^ (m & 7)) & 7;
        f16x8 hv = *(const f16x8*)(h0r + m*HDIM + u8*8);
        *(f16x8*)(smem + m*256 + (8 + w8)*16) = hv;
      }
      f32x4 acc[8][4];
#pragma unroll
      for (int mt = 0; mt < 8; ++mt)
#pragma unroll
        for (int nt = 0; nt < 4; ++nt) { f32x4 z = {0,0,0,0}; acc[mt][nt] = z; }

      // ---- K-loop: 13 windows
#pragma unroll
      for (int wi = 0; wi < 13; ++wi) {
        if (wi == 12)      WAITVM0();
        else if (wi >= 1)  WAITVM8();
        LDSBAR();
        if (wi + 2 < 13) {                   // DMA window wi+2 (cols 128w-64)
          const _Float16* src = h0r + (wi+2)*128 - 64;
          char* dst = smem + ((wi+2)%3)*32768;
#pragma unroll
          for (int i = 0; i < 8; ++i) gld16(src + dmaoff[i], dst + (wv*8+i)*1024);
        }
        if (4*wi + wv < 50) {                // wave's chunk exists
          const char* bs = smem + (wi%3)*32768;
#pragma unroll
          for (int mt = 0; mt < 8; ++mt) {
            f16x8 a = *(const f16x8*)(bs + addrA[mt]);
#pragma unroll
            for (int nt = 0; nt < 4; ++nt)
              acc[mt][nt] = MFMA(a, bw[wi][nt], acc[mt][nt]);
          }
        }
      }
      LDSBAR();

      // ---- staggered K-reduction into gbuf [64 cols][stride 132 f32]
#pragma unroll
      for (int r = 0; r < 4; ++r) {
        int nt = (wv + r) & 3;
#pragma unroll
        for (int mt = 0; mt < 8; ++mt) {
          f32x4 av = (nt==0)?acc[mt][0]:(nt==1)?acc[mt][1]:(nt==2)?acc[mt][2]:acc[mt][3];
          float* p = gbuf + (nt*16 + l15)*132 + (mt*16 + q*4);
          if (r == 0) *(f32x4*)p = av;
          else        { f32x4 o = *(const f32x4*)p; *(f32x4*)p = o + av; }
        }
        LDSBAR();
      }
      // ---- cell update + h0 write
#pragma unroll
      for (int e = 0; e < 8; ++e) {
        int idx = e*256 + tid, m = idx>>4, j = idx&15;
        float gi = gbuf[j*132 + m]        + bg[j];
        float gf = gbuf[(16+j)*132 + m]   + bg[16+j];
        float gg = gbuf[(32+j)*132 + m]   + bg[32+j];
        float go = gbuf[(48+j)*132 + m]   + bg[48+j];
        float co = cst[m*16 + j];
        float cn = sgf(gf)*co + sgf(gi)*thf(gg);
        cst[m*16 + j] = cn;
        h0w[(size_t)m*HDIM + (bid<<4) + j] = (_Float16)(sgf(go)*thf(cn));
      }
      group_bar(c0l, 12u*(unsigned)(s+1), tid);   // L0-only barrier
    }
  } else {
    // ================= LAYER 1: split-K, 12 windows per block ===============
    const int bid1 = bid - NB_L0;            // 0..127
    const int ntile = bid1 >> 1, kt = bid1 & 1;
    const int mybase = kt * 64, otherbase = (1 - kt) * 64;
    float*       partMy = part + (size_t)bid1 * 6144;
    const float* partPn = part + (size_t)(bid1 ^ 1) * 6144;
    unsigned*    flgMy  = pflg + bid1 * 32;
    unsigned*    flgPn  = pflg + (bid1 ^ 1) * 32;
    float*       pbuf   = (float*)(smem + 65536);   // partner-partial stage (24KB)

    for (int p = tid; p < 96; p += 256) {
      int srow = (p/24)*HDIM + ntile*24 + (p%24);
      bg[p] = bih1[srow] + bhh1[srow];
    }
    for (int i = tid; i < 64*24; i += 256) cst[i] = 0.f;
    f16x8 bw1[10][6];                        // windows 0..9 in regs (240 VGPR)
#pragma unroll
    for (int wi = 0; wi < 10; ++wi)
#pragma unroll
      for (int nt = 0; nt < 6; ++nt)
        bw1[wi][nt] = *(const f16x8*)(Wp1 + ((size_t)(bid1*96 + nt*16 + l15))*K1H
                                          + (4*wi + wv)*32 + q*8);
    // windows 10,11 parked in LDS: park[cl][nt][lane], cl = (wi-10)*4 + wv
    for (int idx = tid; idx < 8*6*64; idx += 256) {
      int cl = idx/384, rem = idx - cl*384, nt = rem>>6, l = rem&63;
      f16x8 v = *(const f16x8*)(Wp1 + ((size_t)(bid1*96 + nt*16 + (l&15)))*K1H
                                    + ((10 + (cl>>2))*4 + (cl&3))*32 + (l>>4)*8);
      *(f16x8*)(park + idx*16) = v;
    }
    __syncthreads();

#pragma unroll 1
    for (int s = 1; s <= TSTEPS; ++s) {
      const _Float16* h0r = h0b + (size_t)((s-1)&3)*BH;   // h0(s-1)
      const _Float16* h1r = h1b + (size_t)(s&1)*BH;       // h1(s-2)
      _Float16*       h1w = h1b + (size_t)((s-1)&1)*BH;   // h1(s-1)

      // ktile0 needs h0(s-1); ktile1 reads only h1(s-2) — no c0 wait.
      if (kt == 0) wait_group(c0l, 12u*(unsigned)s, tid);
      const _Float16* kb = kt ? h1r : h0r;

      // prologue: DMA windows 0,1
#pragma unroll
      for (int i = 0; i < 8; ++i) gld16(kb +   0 + dmaoff[i], smem +     0 + (wv*8+i)*1024);
#pragma unroll
      for (int i = 0; i < 8; ++i) gld16(kb + 128 + dmaoff[i], smem + 32768 + (wv*8+i)*1024);
      f32x4 acc[8][6];
#pragma unroll
      for (int mt = 0; mt < 8; ++mt)
#pragma unroll
        for (int nt = 0; nt < 6; ++nt) { f32x4 z = {0,0,0,0}; acc[mt][nt] = z; }

      // ---- K-loop: 12 windows (round-4 engine)
#pragma unroll
      for (int wi = 0; wi < 12; ++wi) {
        if (wi == 11) WAITVM0(); else WAITVM8();
        LDSBAR();
        if (wi + 2 < 12) {
          const _Float16* src = kb + (wi+2)*128;
          char* dst = smem + ((wi+2)%3)*32768;
#pragma unroll
          for (int i = 0; i < 8; ++i) gld16(src + dmaoff[i], dst + (wv*8+i)*1024);
        }
        const char* bs = smem + (wi%3)*32768;
        if (wi < 10) {
#pragma unroll
          for (int mt = 0; mt < 8; ++mt) {
            f16x8 a = *(const f16x8*)(bs + addrA[mt]);
#pragma unroll
            for (int nt = 0; nt < 6; ++nt)
              acc[mt][nt] = MFMA(a, bw1[wi][nt], acc[mt][nt]);
          }
        } else {
          const int cl = (wi-10)*4 + wv;
          f16x8 p0 = *(const f16x8*)(park + ((cl*6+0)*64 + lane)*16);
          f16x8 p1 = *(const f16x8*)(park + ((cl*6+1)*64 + lane)*16);
          f16x8 p2 = *(const f16x8*)(park + ((cl*6+2)*64 + lane)*16);
          f16x8 p3 = *(const f16x8*)(park + ((cl*6+3)*64 + lane)*16);
          f16x8 p4 = *(const f16x8*)(park + ((cl*6+4)*64 + lane)*16);
          f16x8 p5 = *(const f16x8*)(park + ((cl*6+5)*64 + lane)*16);
#pragma unroll
          for (int mt = 0; mt < 8; ++mt) {
            f16x8 a = *(const f16x8*)(bs + addrA[mt]);
            acc[mt][0] = MFMA(a, p0, acc[mt][0]);
            acc[mt][1] = MFMA(a, p1, acc[mt][1]);
            acc[mt][2] = MFMA(a, p2, acc[mt][2]);
            acc[mt][3] = MFMA(a, p3, acc[mt][3]);
            acc[mt][4] = MFMA(a, p4, acc[mt][4]);
            acc[mt][5] = MFMA(a, p5, acc[mt][5]);
          }
        }
      }
      LDSBAR();

      // ---- staggered K-reduction into gbuf [96 cols][stride 132 f32]
#pragma unroll
      for (int r = 0; r < 6; ++r) {
        int nt = wv + r; if (nt >= 6) nt -= 6;
        bool first = (r == ((nt < 4) ? 0 : nt - 3));
#pragma unroll
        for (int mt = 0; mt < 8; ++mt) {
          f32x4 av = (nt==0)?acc[mt][0]:(nt==1)?acc[mt][1]:(nt==2)?acc[mt][2]
                   :(nt==3)?acc[mt][3]:(nt==4)?acc[mt][4]:acc[mt][5];
          float* p = gbuf + (nt*16 + l15)*132 + (mt*16 + q*4);
          if (first) *(f32x4*)p = av;
          else       { f32x4 o = *(const f32x4*)p; *(f32x4*)p = o + av; }
        }
        LDSBAR();
      }

      // ---- write partial gates for OTHER batch half: partMy[b 64][g 96]
      {
        const int mb2 = tid >> 2, gseg = (tid & 3) * 24;
        const int mo = otherbase + mb2;
#pragma unroll
        for (int t = 0; t < 24; t += 2) {
          f32x2 v;
          v[0] = gbuf[(gseg+t  )*132 + mo];
          v[1] = gbuf[(gseg+t+1)*132 + mo];
          *(f32x2*)(partMy + mb2*96 + gseg + t) = v;
        }
      }
      __syncthreads();   // drains stores (vmcnt 0 before barrier)
      if (tid == 0) {
        __hip_atomic_store(flgMy, (unsigned)s, __ATOMIC_RELEASE, __HIP_MEMORY_SCOPE_AGENT);
        while (__hip_atomic_load(flgPn, __ATOMIC_RELAXED, __HIP_MEMORY_SCOPE_AGENT) < (unsigned)s)
          __builtin_amdgcn_s_sleep(1);
        __builtin_amdgcn_fence(__ATOMIC_ACQUIRE, "agent");
      }
      __syncthreads();

      // ---- stage partner partial to LDS (coalesced), then cell update
      for (int e = 0; e < 6; ++e) {
        int idx = (e*256 + tid)*4;           // 6144 f32 = 1536 f32x4
        *(f32x4*)(pbuf + idx) = *(const f32x4*)(partPn + idx);
      }
      __syncthreads();
      {
        const int mb = tid >> 2, jb = (tid & 3) * 6;
        const int m = mybase + mb;
#pragma unroll
        for (int u = 0; u < 6; ++u) {
          int j = jb + u;
          float gi = gbuf[j*132 + m]       + pbuf[mb*96 + j]      + bg[j];
          float gf = gbuf[(24+j)*132 + m]  + pbuf[mb*96 + 24+j]   + bg[24+j];
          float gg = gbuf[(48+j)*132 + m]  + pbuf[mb*96 + 48+j]   + bg[48+j];
          float go = gbuf[(72+j)*132 + m]  + pbuf[mb*96 + 72+j]   + bg[72+j];
          float co = cst[mb*24 + j];
          float cn = sgf(gf)*co + sgf(gi)*thf(gg);
          cst[mb*24 + j] = cn;
          h1w[(size_t)m*HDIM + ntile*24 + j] = (_Float16)(sgf(go)*thf(cn));
        }
      }
      group_bar(c1l, 16u*(unsigned)s, tid);   // L1-only barrier
    }

    // ---- final linear: out = h1(T-1) @ Wlin^T + blin (first L1 block) ----
    if (bid == NB_L0) {
      const _Float16* h1r = h1b + (size_t)((TSTEPS-1)&1)*BH;
      f32x4 a8[8];
#pragma unroll
      for (int i = 0; i < 8; ++i) { f32x4 z = {0,0,0,0}; a8[i] = z; }
      for (int c = wv*12; c < wv*12 + 12; ++c) {
        f16x8 bf = *(const f16x8*)(Wlp + (size_t)l15*HDIM + c*32 + q*8);
#pragma unroll
        for (int mt = 0; mt < 8; ++mt) {
          f16x8 a = *(const f16x8*)(h1r + (size_t)(mt*16 + l15)*HDIM + c*32 + q*8);
          a8[mt] = MFMA(a, bf, a8[mt]);
        }
      }
      float* pl = (float*)smem;
#pragma unroll
      for (int mt = 0; mt < 8; ++mt)
#pragma unroll
        for (int rg = 0; rg < 4; ++rg)
          pl[wv*2048 + (mt*16 + q*4 + rg)*16 + l15] = a8[mt][rg];
      __syncthreads();
      for (int e = tid; e < 640; e += 256) {
        int b = e/5, o = e - 5*b;
        out[e] = blin[o] + pl[b*16+o] + pl[2048 + b*16+o] + pl[4096 + b*16+o] + pl[6144 + b*16+o];
      }
    }
  }
}

extern "C" void kernel_launch(void* const* d_in, const int* in_sizes, int n_in,
                              void* d_out, int out_size, void* d_ws, size_t ws_size,
                              hipStream_t stream) {
  (void)in_sizes; (void)n_in; (void)out_size;
  if (ws_size < WS_NEED) return;

  const float* x    = (const float*)d_in[0];
  const float* Wih0 = (const float*)d_in[1];
  const float* Whh0 = (const float*)d_in[2];
  const float* bih0 = (const float*)d_in[3];
  const float* bhh0 = (const float*)d_in[4];
  const float* Wih1 = (const float*)d_in[5];
  const float* Whh1 = (const float*)d_in[6];
  const float* bih1 = (const float*)d_in[7];
  const float* bhh1 = (const float*)d_in[8];
  const float* Wlin = (const float*)d_in[9];
  const float* blin = (const float*)d_in[10];

  char* ws = (char*)d_ws;
  unsigned*  c0l  = (unsigned*)(ws + OFF_C0);
  unsigned*  c1l  = (unsigned*)(ws + OFF_C1);
  _Float16*  h0b  = (_Float16*)(ws + OFF_H0);
  _Float16*  h1b  = (_Float16*)(ws + OFF_H1);
  _Float16*  Wp0  = (_Float16*)(ws + OFF_WP0);
  _Float16*  Wp1  = (_Float16*)(ws + OFF_WP1);
  _Float16*  Wlp  = (_Float16*)(ws + OFF_WLP);
  float*     part = (float*)(ws + OFF_PART);
  unsigned*  pflg = (unsigned*)(ws + OFF_PFLG);
  float*     out  = (float*)d_out;

  hipMemsetAsync(ws, 0, OFF_WP0, stream);                  // counters + h rings
  hipMemsetAsync(ws + OFF_PFLG, 0, 128*128, stream);       // pair flags
  hipLaunchKernelGGL(convert_weights, dim3(4096), dim3(256), 0, stream,
                     Wih0, Whh0, Wih1, Whh1, Wlin, Wp0, Wp1, Wlp);

  hipFuncSetAttribute((const void*)lstm_persistent,
                      hipFuncAttributeMaxDynamicSharedMemorySize, 160*1024);

  void* args[16];
  args[0]  = (void*)&x;    args[1]  = (void*)&bih0; args[2]  = (void*)&bhh0;
  args[3]  = (void*)&bih1; args[4]  = (void*)&bhh1; args[5]  = (void*)&blin;
  args[6]  = (void*)&Wp0;  args[7]  = (void*)&Wp1;  args[8]  = (void*)&Wlp;
  args[9]  = (void*)&h0b;  args[10] = (void*)&h1b;  args[11] = (void*)&c0l;
  args[12] = (void*)&c1l;  args[13] = (void*)&out;  args[14] = (void*)&part;
  args[15] = (void*)&pflg;
  hipError_t err = hipLaunchCooperativeKernel((const void*)lstm_persistent,
                                              dim3(NBLK), dim3(256),
                                              args, (unsigned)SM_BYTES, stream);
  if (err != hipSuccess) {
    hipLaunchKernelGGL(lstm_persistent, dim3(NBLK), dim3(256), SM_BYTES, stream,
                       x, bih0, bhh0, bih1, bhh1, blin, Wp0, Wp1, Wlp,
                       h0b, h1b, c0l, c1l, out, part, pflg);
  }
}

// Round 6
// 27177.380 us; speedup vs baseline: 1.6919x; 1.6919x over previous
//
// Round 10: R4 engine verbatim; L1 sync re-placement only.
//  (1) c1 end-of-step group-bar -> ADD-ONLY (release). The wait for "all L1
//      done s-1" moves to window 12 (first h1 read), fence-less spin +
//      raw s_barrier -- hidden behind 12 windows of h0 work. Coherence
//      invalidate covered by the once-per-step c0 acquire fence (slot-parity
//      timeline: h1 lines untouched between fences).
//  (2) c0 wait (+acquire fence, free: in-flight=0 after WAITVM0) and
//      next-step w0/w1 prefetch moved into the epilogue -> DMA in flight
//      through reduction/cell; next step starts warm. L1 gbuf -> buffer 2.
//  (3) final linear gated by full wait_group(c1, 16*T). L0 unchanged.
#include <hip/hip_runtime.h>

#define TSTEPS 1024
#define BATCH  128
#define HDIM   1536
#define NB_L0  96
#define NB_L1  128
#define NBLK   (NB_L0 + NB_L1)
#define K0P    1600    // L0 packed K: [0,64)=x+pad, [64,1600)=W_hh0
#define K1P    3072    // L1 packed K: [0,1536)=W_ih1, [1536,3072)=W_hh1

typedef _Float16 f16x8 __attribute__((ext_vector_type(8)));
typedef float    f32x4 __attribute__((ext_vector_type(4)));

// ---- workspace layout (bytes) ----
#define OFF_C0   0ul                                    // 8 lines x 128B
#define OFF_C1   1024ul                                 // 8 lines x 128B
#define OFF_H0   4096ul                                 // ring of 4 slots
#define OFF_H1   (OFF_H0 + 4ul*BATCH*HDIM*2)            // 2 slots
#define OFF_WP0  (OFF_H1 + 2ul*BATCH*HDIM*2)
#define OFF_WP1  (OFF_WP0 + 96ul*64*K0P*2)
#define OFF_WLP  (OFF_WP1 + 128ul*48*K1P*2)
#define WS_NEED  (OFF_WLP + 16ul*HDIM*2)                // ~59.8 MB

// ---- dynamic LDS layout (bytes) — round-4 map ----
#define SM_PARK  98304     // park: 16 chunks x 3KB = 48KB (L1 only)
#define SM_CST   147456
#define SM_BG    155648
#define SM_BYTES 155904

#define MFMA(a,b,c) __builtin_amdgcn_mfma_f32_16x16x32_f16(a,b,c,0,0,0)
#define LDSBAR()  asm volatile("s_waitcnt lgkmcnt(0)\n\ts_barrier" ::: "memory")
#define WAITVM8() asm volatile("s_waitcnt vmcnt(8)" ::: "memory")
#define WAITVM0() asm volatile("s_waitcnt vmcnt(0)" ::: "memory")

__device__ __forceinline__ float sgf(float x) { return 1.f/(1.f + __expf(-x)); }
__device__ __forceinline__ float thf(float x) { float e = __expf(2.f*x); return 1.f - 2.f/(e+1.f); }

__device__ __forceinline__ void gld16(const _Float16* g, char* lds) {
  __builtin_amdgcn_global_load_lds(
      (const __attribute__((address_space(1))) unsigned int*)g,
      (__attribute__((address_space(3))) unsigned int*)lds, 16, 0, 0);
}

// Group barrier: add 1 to my line (release), spin until all 8 lines hit
// per-line target, acquire, resync.
__device__ __forceinline__ void group_bar(unsigned* lines, unsigned target, int tid) {
  __syncthreads();   // all stores (incl. h) issued; drains vmcnt/lgkm
  if (tid == 0)
    __hip_atomic_fetch_add(lines + (blockIdx.x & 7)*32, 1u,
                           __ATOMIC_RELEASE, __HIP_MEMORY_SCOPE_AGENT);
  if (tid < 8) {
    while (__hip_atomic_load(lines + tid*32, __ATOMIC_RELAXED,
                             __HIP_MEMORY_SCOPE_AGENT) < target)
      __builtin_amdgcn_s_sleep(1);
    __builtin_amdgcn_fence(__ATOMIC_ACQUIRE, "agent");
  }
  __syncthreads();
}

// Cross-group wait (no add): poll other group's 8 lines to target, acquire.
__device__ __forceinline__ void wait_group(unsigned* lines, unsigned target, int tid) {
  if (tid < 8) {
    while (__hip_atomic_load(lines + tid*32, __ATOMIC_RELAXED,
                             __HIP_MEMORY_SCOPE_AGENT) < target)
      __builtin_amdgcn_s_sleep(1);
    __builtin_amdgcn_fence(__ATOMIC_ACQUIRE, "agent");
  }
  __syncthreads();
}

// ---- weight repack fp32 -> fp16 into per-block packed rows ----
__global__ void convert_weights(const float* __restrict__ Wih0, const float* __restrict__ Whh0,
                                const float* __restrict__ Wih1, const float* __restrict__ Whh1,
                                const float* __restrict__ Wlin,
                                _Float16* __restrict__ Wp0, _Float16* __restrict__ Wp1,
                                _Float16* __restrict__ Wlp) {
  const unsigned N0 = 96u*64u*K0P, N1 = 128u*48u*K1P, N2 = 16u*HDIM;
  const unsigned NT = N0 + N1 + N2;
  for (unsigned i = blockIdx.x*blockDim.x + threadIdx.x; i < NT; i += gridDim.x*blockDim.x) {
    if (i < N0) {           // L0: [blk 96][p 64][k 1600], p = gate*16 + j
      unsigned blk = i / (64u*K0P), r = i - blk*64u*K0P;
      unsigned p = r / K0P, kk = r - p*K0P;
      unsigned srow = (p>>4)*HDIM + blk*16 + (p&15);
      float v;
      if (kk < 64u) v = (kk < 6u) ? Wih0[srow*6 + kk] : 0.f;
      else          v = Whh0[(size_t)srow*HDIM + (kk-64u)];
      Wp0[i] = (_Float16)v;
    } else if (i < N0 + N1) { // L1: [blk 128][p 48][k 3072], p = gate*12 + j
      unsigned ii = i - N0;
      unsigned blk = ii / (48u*K1P), r = ii - blk*48u*K1P;
      unsigned p = r / K1P, kk = r - p*K1P;
      unsigned srow = (p/12u)*HDIM + blk*12 + (p%12u);
      float v = (kk < (unsigned)HDIM) ? Wih1[(size_t)srow*HDIM + kk]
                                      : Whh1[(size_t)srow*HDIM + (kk-HDIM)];
      Wp1[ii] = (_Float16)v;
    } else {                 // final linear 16 x 1536 (rows >=5 zero)
      unsigned ii = i - N0 - N1;
      unsigned rr = ii / HDIM, k = ii - rr*HDIM;
      Wlp[ii] = (_Float16)(rr < 5 ? Wlin[rr*HDIM + k] : 0.f);
    }
  }
}

__global__ __launch_bounds__(256, 1) void lstm_persistent(
    const float* __restrict__ xall,
    const float* __restrict__ bih0, const float* __restrict__ bhh0,
    const float* __restrict__ bih1, const float* __restrict__ bhh1,
    const float* __restrict__ blin,
    const _Float16* __restrict__ Wp0, const _Float16* __restrict__ Wp1,
    const _Float16* __restrict__ Wlp,
    _Float16* __restrict__ h0b, _Float16* __restrict__ h1b,
    unsigned* __restrict__ c0l, unsigned* __restrict__ c1l,
    float* __restrict__ out)
{
  extern __shared__ __align__(16) char smem[];
  char*  park = smem + SM_PARK;
  float* cst  = (float*)(smem + SM_CST);
  float* bg   = (float*)(smem + SM_BG);
  float* gbuf = (float*)smem;            // L0 epilogue overlay (buffers 0..1)

  const int tid = threadIdx.x, bid = blockIdx.x;
  const int wv = tid >> 6, lane = tid & 63, q = lane >> 4, l15 = lane & 15;
  const int BH = BATCH*HDIM;

  // DMA lane offsets: instr i stages rows [wv*32+i*4, +4), swizzled cols.
  int dmaoff[8];
#pragma unroll
  for (int i = 0; i < 8; ++i) {
    int m = wv*32 + i*4 + (lane>>4), w16 = lane & 15;
    int u = (w16 & 8) | ((w16 ^ (m & 7)) & 7);
    dmaoff[i] = m*HDIM + u*8;
  }
  // A-frag LDS byte addrs within a window buffer (this wave reads chunk #wv).
  const int uA = wv*4 + q;
  int addrA[8];
#pragma unroll
  for (int mt = 0; mt < 8; ++mt) {
    int m = mt*16 + l15;
    int swz = (uA & 8) | ((uA ^ (m & 7)) & 7);
    addrA[mt] = m*256 + swz*16;
  }

  if (bid < NB_L0) {
    // ================= LAYER 0 (round-4 verbatim): 13 windows ===============
    for (int p = tid; p < 64; p += 256) {
      int srow = (p>>4)*HDIM + (bid<<4) + (p&15);
      bg[p] = bih0[srow] + bhh0[srow];
    }
    for (int i = tid; i < BATCH*16; i += 256) cst[i] = 0.f;
    f16x8 bw[13][4];
#pragma unroll
    for (int wi = 0; wi < 13; ++wi)
#pragma unroll
      for (int nt = 0; nt < 4; ++nt)
        bw[wi][nt] = *(const f16x8*)(Wp0 + ((size_t)(bid*64 + nt*16 + l15))*K0P
                                         + (4*wi + wv)*32 + q*8);
    __syncthreads();

#pragma unroll 1
    for (int s = 0; s < TSTEPS; ++s) {
      // ring-overwrite guard: slot s&3 was read by L1 step s-3; wait it done.
      if (s >= 4) wait_group(c1l, 16u*(unsigned)(s-3), tid);

      const _Float16* h0r = h0b + (size_t)((s+3)&3)*BH;   // h0(s-1)
      _Float16*       h0w = h0b + (size_t)(s&3)*BH;       // h0(s)
      const float*    xs  = xall + (size_t)s*BATCH*6;

      // ---- prologue: DMA window1; plain-stage window0 (x-part + h cols 0..63)
#pragma unroll
      for (int i = 0; i < 8; ++i)
        gld16(h0r + 64 + dmaoff[i], smem + 32768 + (wv*8+i)*1024);
#pragma unroll
      for (int i = 0; i < 4; ++i) {          // x-part, slots u<8 of window0
        int sidx = i*256 + tid, m = sidx>>3, w8 = sidx&7;
        int u = w8 ^ (m & 7);
        f16x8 v = {0,0,0,0,0,0,0,0};
        if (u == 0) {
#pragma unroll
          for (int j = 0; j < 6; ++j) v[j] = (_Float16)xs[m*6 + j];
        }
        *(f16x8*)(smem + m*256 + w8*16) = v;
      }
#pragma unroll
      for (int i = 0; i < 4; ++i) {          // h cols [0,64) -> slots w in [8,16)
        int sidx = i*256 + tid, m = sidx>>3, w8 = sidx&7;
        int u8 = (w8 ^ (m & 7)) & 7;
        f16x8 hv = *(const f16x8*)(h0r + m*HDIM + u8*8);
        *(f16x8*)(smem + m*256 + (8 + w8)*16) = hv;
      }
      f32x4 acc[8][4];
#pragma unroll
      for (int mt = 0; mt < 8; ++mt)
#pragma unroll
        for (int nt = 0; nt < 4; ++nt) { f32x4 z = {0,0,0,0}; acc[mt][nt] = z; }

      // ---- K-loop: 13 windows
#pragma unroll
      for (int wi = 0; wi < 13; ++wi) {
        if (wi == 12)      WAITVM0();
        else if (wi >= 1)  WAITVM8();
        LDSBAR();
        if (wi + 2 < 13) {                   // DMA window wi+2 (cols 128w-64)
          const _Float16* src = h0r + (wi+2)*128 - 64;
          char* dst = smem + ((wi+2)%3)*32768;
#pragma unroll
          for (int i = 0; i < 8; ++i) gld16(src + dmaoff[i], dst + (wv*8+i)*1024);
        }
        if (4*wi + wv < 50) {                // wave's chunk exists
          const char* bs = smem + (wi%3)*32768;
#pragma unroll
          for (int mt = 0; mt < 8; ++mt) {
            f16x8 a = *(const f16x8*)(bs + addrA[mt]);
#pragma unroll
            for (int nt = 0; nt < 4; ++nt)
              acc[mt][nt] = MFMA(a, bw[wi][nt], acc[mt][nt]);
          }
        }
      }
      LDSBAR();

      // ---- staggered K-reduction into gbuf [64 cols][stride 132 f32]
#pragma unroll
      for (int r = 0; r < 4; ++r) {
        int nt = (wv + r) & 3;
#pragma unroll
        for (int mt = 0; mt < 8; ++mt) {
          f32x4 av = (nt==0)?acc[mt][0]:(nt==1)?acc[mt][1]:(nt==2)?acc[mt][2]:acc[mt][3];
          float* p = gbuf + (nt*16 + l15)*132 + (mt*16 + q*4);
          if (r == 0) *(f32x4*)p = av;
          else        { f32x4 o = *(const f32x4*)p; *(f32x4*)p = o + av; }
        }
        LDSBAR();
      }
      // ---- cell update + h0 write
#pragma unroll
      for (int e = 0; e < 8; ++e) {
        int idx = e*256 + tid, m = idx>>4, j = idx&15;
        float gi = gbuf[j*132 + m]        + bg[j];
        float gf = gbuf[(16+j)*132 + m]   + bg[16+j];
        float gg = gbuf[(32+j)*132 + m]   + bg[32+j];
        float go = gbuf[(48+j)*132 + m]   + bg[48+j];
        float co = cst[m*16 + j];
        float cn = sgf(gf)*co + sgf(gi)*thf(gg);
        cst[m*16 + j] = cn;
        h0w[(size_t)m*HDIM + (bid<<4) + j] = (_Float16)(sgf(go)*thf(cn));
      }
      group_bar(c0l, 12u*(unsigned)(s+1), tid);   // L0-only barrier
    }
  } else {
    // ======== LAYER 1: R4 engine; sync re-placed (add-only c1, mid wait) ====
    const int bid1 = bid - NB_L0;
    float* gbuf1 = (float*)(smem + 65536);   // reduction overlay on buffer 2
    for (int p = tid; p < 48; p += 256) {
      int srow = (p/12)*HDIM + bid1*12 + (p%12);
      bg[p] = bih1[srow] + bhh1[srow];
    }
    for (int i = tid; i < BATCH*12; i += 256) cst[i] = 0.f;
    f16x8 bw1[20][3];                        // windows 0..19 in regs
#pragma unroll
    for (int wi = 0; wi < 20; ++wi)
#pragma unroll
      for (int nt = 0; nt < 3; ++nt)
        bw1[wi][nt] = *(const f16x8*)(Wp1 + ((size_t)(bid1*48 + nt*16 + l15))*K1P
                                          + (4*wi + wv)*32 + q*8);
    // windows 20..23 parked in LDS: park[cl][nt][lane], cl = (wi-20)*4 + wv
    for (int idx = tid; idx < 16*3*64; idx += 256) {
      int cl = idx/192, rem = idx - cl*192, nt = rem>>6, l = rem&63;
      f16x8 v = *(const f16x8*)(Wp1 + ((size_t)(bid1*48 + nt*16 + (l&15)))*K1P
                                    + (80 + cl)*32 + (l>>4)*8);
      *(f16x8*)(park + idx*16) = v;
    }
    __syncthreads();

    // initial c0 wait (acquire) + prologue DMA for step 1
    wait_group(c0l, 12u, tid);
    {
      const _Float16* h0r1 = h0b;            // h0(0), slot 0
#pragma unroll
      for (int i = 0; i < 8; ++i) gld16(h0r1 +   0 + dmaoff[i], smem +     0 + (wv*8+i)*1024);
#pragma unroll
      for (int i = 0; i < 8; ++i) gld16(h0r1 + 128 + dmaoff[i], smem + 32768 + (wv*8+i)*1024);
    }

#pragma unroll 1
    for (int s = 1; s <= TSTEPS; ++s) {
      const _Float16* h0r = h0b + (size_t)((s-1)&3)*BH;   // h0(s-1)
      const _Float16* h1r = h1b + (size_t)(s&1)*BH;       // h1(s-2)
      _Float16*       h1w = h1b + (size_t)((s-1)&1)*BH;   // h1(s-1)

      f32x4 acc[8][3];
#pragma unroll
      for (int mt = 0; mt < 8; ++mt)
#pragma unroll
        for (int nt = 0; nt < 3; ++nt) { f32x4 z = {0,0,0,0}; acc[mt][nt] = z; }

      // ---- K-loop: 24 windows (w0,w1 already in flight from epilogue/prologue)
#pragma unroll
      for (int wi = 0; wi < 24; ++wi) {
        if (wi == 10) {
          // fence-less wait: all L1 done step s-1 (h1(s-2) published) before
          // issuing the first h1-window DMA. No syncthreads -> no vmcnt drain.
          const unsigned tgt = 16u*(unsigned)(s-1);
          while (__hip_atomic_load(c1l + (tid&7)*32, __ATOMIC_RELAXED,
                                   __HIP_MEMORY_SCOPE_AGENT) < tgt)
            __builtin_amdgcn_s_sleep(1);
          asm volatile("s_barrier" ::: "memory");
        }
        if (wi == 23) WAITVM0(); else WAITVM8();
        LDSBAR();
        if (wi + 2 < 24) {
          int wn = wi + 2;
          const _Float16* src = (wn < 12) ? (h0r + wn*128) : (h1r + (wn-12)*128);
          char* dst = smem + (wn%3)*32768;
#pragma unroll
          for (int i = 0; i < 8; ++i) gld16(src + dmaoff[i], dst + (wv*8+i)*1024);
        }
        const char* bs = smem + (wi%3)*32768;
        if (wi < 20) {
#pragma unroll
          for (int mt = 0; mt < 8; ++mt) {
            f16x8 a = *(const f16x8*)(bs + addrA[mt]);
#pragma unroll
            for (int nt = 0; nt < 3; ++nt)
              acc[mt][nt] = MFMA(a, bw1[wi][nt], acc[mt][nt]);
          }
        } else {
          const int cl = (wi-20)*4 + wv;
          f16x8 p0 = *(const f16x8*)(park + ((cl*3+0)*64 + lane)*16);
          f16x8 p1 = *(const f16x8*)(park + ((cl*3+1)*64 + lane)*16);
          f16x8 p2 = *(const f16x8*)(park + ((cl*3+2)*64 + lane)*16);
#pragma unroll
          for (int mt = 0; mt < 8; ++mt) {
            f16x8 a = *(const f16x8*)(bs + addrA[mt]);
            acc[mt][0] = MFMA(a, p0, acc[mt][0]);
            acc[mt][1] = MFMA(a, p1, acc[mt][1]);
            acc[mt][2] = MFMA(a, p2, acc[mt][2]);
          }
        }
      }
      LDSBAR();

      // ---- moved c0 wait (acquire; in-flight=0 so the drain is free) and
      //      next-step w0/w1 prefetch: DMA overlaps reduction+cell below.
      if (s < TSTEPS) {
        wait_group(c0l, 12u*(unsigned)(s+1), tid);
        const _Float16* h0n = h0b + (size_t)(s&3)*BH;     // h0(s)
#pragma unroll
        for (int i = 0; i < 8; ++i) gld16(h0n +   0 + dmaoff[i], smem +     0 + (wv*8+i)*1024);
#pragma unroll
        for (int i = 0; i < 8; ++i) gld16(h0n + 128 + dmaoff[i], smem + 32768 + (wv*8+i)*1024);
      }

      // ---- staggered K-reduction (3 ntiles) into gbuf1 (buffer 2)
#pragma unroll
      for (int r = 0; r < 4; ++r) {
        int nt = (wv + r) & 3;
        if (nt < 3) {
#pragma unroll
          for (int mt = 0; mt < 8; ++mt) {
            f32x4 av = (nt==0)?acc[mt][0]:(nt==1)?acc[mt][1]:acc[mt][2];
            float* p = gbuf1 + (nt*16 + l15)*132 + (mt*16 + q*4);
            if (r == 0) *(f32x4*)p = av;
            else        { f32x4 o = *(const f32x4*)p; *(f32x4*)p = o + av; }
          }
        }
        LDSBAR();
      }
#pragma unroll
      for (int e = 0; e < 8; ++e) {
        int idx = e*256 + tid, m = idx>>4, j = idx&15;
        if (j < 12) {
          float gi = gbuf1[j*132 + m]        + bg[j];
          float gf = gbuf1[(12+j)*132 + m]   + bg[12+j];
          float gg = gbuf1[(24+j)*132 + m]   + bg[24+j];
          float go = gbuf1[(36+j)*132 + m]   + bg[36+j];
          float co = cst[m*12 + j];
          float cn = sgf(gf)*co + sgf(gi)*thf(gg);
          cst[m*12 + j] = cn;
          h1w[(size_t)m*HDIM + bid1*12 + j] = (_Float16)(sgf(go)*thf(cn));
        }
      }
      // ---- add-only release (no spin): publishes h1(s-1) + "done reading
      //      h0(s-1)". The wait counterpart is the wi==10 spin of step s+1.
      __syncthreads();   // drains h1 stores (vmcnt) per-wave before the add
      if (tid == 0)
        __hip_atomic_fetch_add(c1l + (bid & 7)*32, 1u,
                               __ATOMIC_RELEASE, __HIP_MEMORY_SCOPE_AGENT);
    }

    // full rendezvous (with acquire fence) before reading all blocks' h1(T-1)
    wait_group(c1l, 16u*(unsigned)TSTEPS, tid);

    // ---- final linear: out = h1(T-1) @ Wlin^T + blin (first L1 block) ----
    if (bid == NB_L0) {
      const _Float16* h1r = h1b + (size_t)((TSTEPS-1)&1)*BH;
      f32x4 a8[8];
#pragma unroll
      for (int i = 0; i < 8; ++i) { f32x4 z = {0,0,0,0}; a8[i] = z; }
      for (int c = wv*12; c < wv*12 + 12; ++c) {
        f16x8 bf = *(const f16x8*)(Wlp + (size_t)l15*HDIM + c*32 + q*8);
#pragma unroll
        for (int mt = 0; mt < 8; ++mt) {
          f16x8 a = *(const f16x8*)(h1r + (size_t)(mt*16 + l15)*HDIM + c*32 + q*8);
          a8[mt] = MFMA(a, bf, a8[mt]);
        }
      }
      float* pl = (float*)smem;
#pragma unroll
      for (int mt = 0; mt < 8; ++mt)
#pragma unroll
        for (int rg = 0; rg < 4; ++rg)
          pl[wv*2048 + (mt*16 + q*4 + rg)*16 + l15] = a8[mt][rg];
      __syncthreads();
      for (int e = tid; e < 640; e += 256) {
        int b = e/5, o = e - 5*b;
        out[e] = blin[o] + pl[b*16+o] + pl[2048 + b*16+o] + pl[4096 + b*16+o] + pl[6144 + b*16+o];
      }
    }
  }
}

extern "C" void kernel_launch(void* const* d_in, const int* in_sizes, int n_in,
                              void* d_out, int out_size, void* d_ws, size_t ws_size,
                              hipStream_t stream) {
  (void)in_sizes; (void)n_in; (void)out_size;
  if (ws_size < WS_NEED) return;

  const float* x    = (const float*)d_in[0];
  const float* Wih0 = (const float*)d_in[1];
  const float* Whh0 = (const float*)d_in[2];
  const float* bih0 = (const float*)d_in[3];
  const float* bhh0 = (const float*)d_in[4];
  const float* Wih1 = (const float*)d_in[5];
  const float* Whh1 = (const float*)d_in[6];
  const float* bih1 = (const float*)d_in[7];
  const float* bhh1 = (const float*)d_in[8];
  const float* Wlin = (const float*)d_in[9];
  const float* blin = (const float*)d_in[10];

  char* ws = (char*)d_ws;
  unsigned*  c0l = (unsigned*)(ws + OFF_C0);
  unsigned*  c1l = (unsigned*)(ws + OFF_C1);
  _Float16*  h0b = (_Float16*)(ws + OFF_H0);
  _Float16*  h1b = (_Float16*)(ws + OFF_H1);
  _Float16*  Wp0 = (_Float16*)(ws + OFF_WP0);
  _Float16*  Wp1 = (_Float16*)(ws + OFF_WP1);
  _Float16*  Wlp = (_Float16*)(ws + OFF_WLP);
  float*     out = (float*)d_out;

  hipMemsetAsync(ws, 0, OFF_WP0, stream);   // counters + h rings
  hipLaunchKernelGGL(convert_weights, dim3(4096), dim3(256), 0, stream,
                     Wih0, Whh0, Wih1, Whh1, Wlin, Wp0, Wp1, Wlp);

  hipFuncSetAttribute((const void*)lstm_persistent,
                      hipFuncAttributeMaxDynamicSharedMemorySize, 160*1024);

  void* args[14];
  args[0]  = (void*)&x;    args[1]  = (void*)&bih0; args[2]  = (void*)&bhh0;
  args[3]  = (void*)&bih1; args[4]  = (void*)&bhh1; args[5]  = (void*)&blin;
  args[6]  = (void*)&Wp0;  args[7]  = (void*)&Wp1;  args[8]  = (void*)&Wlp;
  args[9]  = (void*)&h0b;  args[10] = (void*)&h1b;  args[11] = (void*)&c0l;
  args[12] = (void*)&c1l;  args[13] = (void*)&out;
  hipError_t err = hipLaunchCooperativeKernel((const void*)lstm_persistent,
                                              dim3(NBLK), dim3(256),
                                              args, (unsigned)SM_BYTES, stream);
  if (err != hipSuccess) {
    hipLaunchKernelGGL(lstm_persistent, dim3(NBLK), dim3(256), SM_BYTES, stream,
                       x, bih0, bhh0, bih1, bhh1, blin, Wp0, Wp1, Wlp,
                       h0b, h1b, c0l, c1l, out);
  }
}